// Round 10
// baseline (14520.528 us; speedup 1.0000x reference)
//
#include <hip/hip_runtime.h>

#define D 64
// 4 slice-groups of 16 floats (64B rows -> one cache line per gather, no
// amplification). XCD pair (2g,2g+1) serves slice-group g: each XCD handles one
// half of the destination nodes, gathering from ALL source rows of its group
// (5.76 MB vs 4 MB L2 -> ~69% L2 hit, misses refill from L3). blockIdx%8 is the
// XCD id under the round-robin workgroup dispatch heuristic.
// Streams with no reuse (acc, y_out) are nontemporal so they don't evict the
// hot slice; csr index reads are PLAIN loads (8B-stride stream, L1 captures it).

// HIP's float4 is a class type; the nontemporal builtins need a native vector.
typedef float f4raw __attribute__((ext_vector_type(4)));

static __device__ __forceinline__ float4 nt_load4(const float4* p) {
    f4raw v = __builtin_nontemporal_load((const f4raw*)p);
    float4 r;
    r.x = v.x; r.y = v.y; r.z = v.z; r.w = v.w;
    return r;
}

static __device__ __forceinline__ void nt_store4(const float4& v, float4* p) {
    f4raw r;
    r.x = v.x; r.y = v.y; r.z = v.z; r.w = v.w;
    __builtin_nontemporal_store(r, (f4raw*)p);
}

__global__ void degree_kernel(const int* __restrict__ col, int* __restrict__ deg, int E) {
    int e = blockIdx.x * blockDim.x + threadIdx.x;
    if (e < E) atomicAdd(&deg[col[e]], 1);
}

__global__ void dinv_kernel(const int* __restrict__ deg, float* __restrict__ dinv, int n) {
    int i = blockIdx.x * blockDim.x + threadIdx.x;
    if (i < n) {
        int d = deg[i];
        dinv[i] = (d > 0) ? (1.0f / sqrtf((float)d)) : 0.0f;
    }
}

// Single-workgroup exclusive scan over N elements (runs once per call).
__global__ __launch_bounds__(1024) void scan_kernel(const int* __restrict__ deg,
                                                    int* __restrict__ row_ptr, int n) {
    __shared__ int wsum[16];
    const int tid = threadIdx.x;
    const int lane = tid & 63;
    const int w = tid >> 6;
    int carry = 0;
    for (int base = 0; base < n; base += 1024) {
        int i = base + tid;
        int v = (i < n) ? deg[i] : 0;
        int x = v;
#pragma unroll
        for (int off = 1; off < 64; off <<= 1) {
            int y = __shfl_up(x, off);
            if (lane >= off) x += y;
        }
        if (lane == 63) wsum[w] = x;
        __syncthreads();
        if (w == 0 && lane < 16) {
            int s = wsum[lane];
#pragma unroll
            for (int off = 1; off < 16; off <<= 1) {
                int y = __shfl_up(s, off);
                if (lane >= off) s += y;
            }
            wsum[lane] = s;
        }
        __syncthreads();
        int pref = (w > 0) ? wsum[w - 1] : 0;
        if (i < n) row_ptr[i] = carry + pref + (x - v);
        carry += wsum[15];
        __syncthreads();
    }
    if (tid == 0) row_ptr[n] = carry;
}

// CSR build: only src ids (the y-transform removed per-edge weights).
__global__ void scatter_kernel(const int* __restrict__ row, const int* __restrict__ col,
                               const int* __restrict__ row_ptr, int* __restrict__ cursor,
                               int* __restrict__ csr_src, int E) {
    int e = blockIdx.x * blockDim.x + threadIdx.x;
    if (e < E) {
        int s = row[e];
        int d = col[e];
        int pos = row_ptr[d] + atomicAdd(&cursor[d], 1);
        csr_src[pos] = s;
    }
}

// y0 = dinv ⊙ emb and acc0 = emb, both in grouped layout:
// float4 idx = ((g*n + node)*4 + h), g=0..3 (16-float slice-group), h=0..3.
__global__ void init_kernel(const float4* __restrict__ emb, const float* __restrict__ dinv,
                            float4* __restrict__ y, float4* __restrict__ accS, int n) {
    int e = blockIdx.x * blockDim.x + threadIdx.x;   // over n*16 float4s
    if (e < n * 16) {
        int node = e >> 4;
        int r = e & 15;      // float4 index within the 64-dim row
        int g = r >> 2;
        int h = r & 3;
        float dv = dinv[node];
        float4 v = emb[e];
        size_t idx = ((size_t)g * n + node) * 4 + h;
        accS[idx] = v;
        float4 yv;
        yv.x = v.x * dv; yv.y = v.y * dv; yv.z = v.z * dv; yv.w = v.w * dv;
        y[idx] = yv;
    }
}

// One wave handles 16 dst nodes (of this XCD's half) for ONE slice-group.
// 4 lanes per node: lane h owns float4 h of the 64B row -> a node's gather is
// exactly one cache line. 2-stage software pipeline: csr indices prefetched 2
// iterations ahead, y-gathers issued 1 iteration ahead. Tail lanes use
// mask-FMAs (gather of node 0 is always safe and coalesces onto a hot line).
__global__ __launch_bounds__(256) void spmm_slice_kernel(
    const float4* __restrict__ y_in, float4* __restrict__ y_out,
    float4* __restrict__ accS,
    const int* __restrict__ row_ptr, const int* __restrict__ csr_src,
    const float* __restrict__ dinv, int n) {
    const int xcd = blockIdx.x & 7;      // XCD under round-robin mapping
    const int g = xcd >> 1;              // slice-group 0..3
    const int half = xcd & 1;            // destination-node half
    const int chunk = blockIdx.x >> 3;
    const int wv = threadIdx.x >> 6;
    const int lane = threadIdx.x & 63;
    const int slot = lane >> 2;          // node slot 0..15
    const int h = lane & 3;              // float4 within the 64B row
    const int nh = (n + 1) >> 1;
    const int local = chunk * 64 + wv * 16 + slot;
    const int v = half * nh + local;
    const bool valid = (local < nh) && (v < n);

    int beg = 0, cnt = 0;
    if (valid) {
        beg = row_ptr[v];
        cnt = row_ptr[v + 1] - beg;
    }
    // wave-wide max edge count (the 4 lanes of a slot have equal cnt)
    int mx = cnt;
#pragma unroll
    for (int off = 4; off < 64; off <<= 1) {
        int o = __shfl_xor(mx, off);
        mx = (o > mx) ? o : mx;
    }

    const float4* __restrict__ ybase = y_in + ((size_t)g * n) * 4 + h;

    float4 sum0; sum0.x = sum0.y = sum0.z = sum0.w = 0.f;
    float4 sum1; sum1.x = sum1.y = sum1.z = sum1.w = 0.f;

    // pipeline prologue: indices for iters 0 and 1, gathers for iter 0
    int i0c = (0 < cnt) ? csr_src[beg] : 0;
    int i1c = (1 < cnt) ? csr_src[beg + 1] : 0;
    int i0n = (2 < cnt) ? csr_src[beg + 2] : 0;
    int i1n = (3 < cnt) ? csr_src[beg + 3] : 0;
    float4 g0 = ybase[(size_t)i0c * 4];
    float4 g1 = ybase[(size_t)i1c * 4];

    for (int k = 0; k < mx; k += 2) {
        // issue next iteration's gathers
        float4 n0 = ybase[(size_t)i0n * 4];
        float4 n1 = ybase[(size_t)i1n * 4];
        // prefetch indices two iterations ahead
        const int kf = k + 4;
        int i0f = (kf < cnt) ? csr_src[beg + kf] : 0;
        int i1f = (kf + 1 < cnt) ? csr_src[beg + kf + 1] : 0;
        // consume current gathers under mask
        const float m0 = (k < cnt) ? 1.f : 0.f;
        const float m1 = (k + 1 < cnt) ? 1.f : 0.f;
        sum0.x = fmaf(m0, g0.x, sum0.x); sum0.y = fmaf(m0, g0.y, sum0.y);
        sum0.z = fmaf(m0, g0.z, sum0.z); sum0.w = fmaf(m0, g0.w, sum0.w);
        sum1.x = fmaf(m1, g1.x, sum1.x); sum1.y = fmaf(m1, g1.y, sum1.y);
        sum1.z = fmaf(m1, g1.z, sum1.z); sum1.w = fmaf(m1, g1.w, sum1.w);
        // rotate pipeline
        g0 = n0; g1 = n1; i0n = i0f; i1n = i1f;
    }
    sum0.x += sum1.x; sum0.y += sum1.y; sum0.z += sum1.z; sum0.w += sum1.w;

    if (valid) {
        const float dv = dinv[v];
        float4 xn;                         // x_{l+1} slice = dinv[v] * sum
        xn.x = dv * sum0.x; xn.y = dv * sum0.y; xn.z = dv * sum0.z; xn.w = dv * sum0.w;

        const size_t idx = ((size_t)g * n + v) * 4 + h;
        // acc += x_{l+1} (grouped layout, fully coalesced, nontemporal: no reuse)
        float4 a = nt_load4(&accS[idx]);
        a.x += xn.x; a.y += xn.y; a.z += xn.z; a.w += xn.w;
        nt_store4(a, &accS[idx]);

        // y_{l+1} = dinv[v] * x_{l+1}
        float4 yn;
        yn.x = dv * xn.x; yn.y = dv * xn.y; yn.z = dv * xn.z; yn.w = dv * xn.w;
        nt_store4(yn, &y_out[idx]);
    }
}

// Un-transpose the grouped accumulator into d_out and apply the 1/(L+1) scale.
__global__ void finalize_kernel(const float4* __restrict__ accS, float4* __restrict__ out,
                                float f, int n) {
    int i = blockIdx.x * blockDim.x + threadIdx.x;   // over n*16 float4s
    if (i < n * 16) {
        int node = i >> 4;
        int r = i & 15;
        int g = r >> 2;
        int h = r & 3;
        float4 a = accS[((size_t)g * n + node) * 4 + h];
        a.x *= f; a.y *= f; a.z *= f; a.w *= f;
        out[i] = a;
    }
}

extern "C" void kernel_launch(void* const* d_in, const int* in_sizes, int n_in,
                              void* d_out, int out_size, void* d_ws, size_t ws_size,
                              hipStream_t stream) {
    const float* emb = (const float*)d_in[0];
    const int* eidx = (const int*)d_in[1];
    const int N = in_sizes[0] / D;   // 90000
    const int E = in_sizes[1] / 2;   // 3000000
    const int L = 100;
    const int* row = eidx;       // edge_index[0]
    const int* col = eidx + E;   // edge_index[1]

    size_t off = 0;
    auto alloc = [&](size_t bytes) -> void* {
        void* p = (char*)d_ws + off;
        off += (bytes + 255) & ~(size_t)255;
        return p;
    };
    int*   deg     = (int*)alloc((size_t)N * 4);
    float* dinv    = (float*)alloc((size_t)N * 4);
    int*   row_ptr = (int*)alloc((size_t)(N + 1) * 4);
    int*   cursor  = (int*)alloc((size_t)N * 4);
    int*   csr_src = (int*)alloc((size_t)E * 4);
    float* yA      = (float*)alloc((size_t)N * D * 4);
    float* yB      = (float*)alloc((size_t)N * D * 4);
    float* accS    = (float*)alloc((size_t)N * D * 4);

    (void)hipMemsetAsync(deg, 0, (size_t)N * 4, stream);
    (void)hipMemsetAsync(cursor, 0, (size_t)N * 4, stream);

    degree_kernel<<<(E + 255) / 256, 256, 0, stream>>>(col, deg, E);
    dinv_kernel<<<(N + 255) / 256, 256, 0, stream>>>(deg, dinv, N);
    scan_kernel<<<1, 1024, 0, stream>>>(deg, row_ptr, N);
    scatter_kernel<<<(E + 255) / 256, 256, 0, stream>>>(row, col, row_ptr, cursor, csr_src, E);

    // y_0 = dinv ⊙ emb and acc_0 = emb, both in grouped layout
    init_kernel<<<(N * 16 + 255) / 256, 256, 0, stream>>>((const float4*)emb, dinv,
                                                          (float4*)yA, (float4*)accS, N);

    const int nh = (N + 1) / 2;
    const int spmm_blocks = 8 * ((nh + 63) / 64);
    const float4* yin = (const float4*)yA;
    float4* yout = (float4*)yB;
    for (int l = 0; l < L; ++l) {
        spmm_slice_kernel<<<spmm_blocks, 256, 0, stream>>>(yin, yout, (float4*)accS,
                                                           row_ptr, csr_src, dinv, N);
        const float4* t = yin;
        yin = (const float4*)yout;
        yout = (float4*)t;
    }

    const int n4 = N * D / 4;
    finalize_kernel<<<(n4 + 255) / 256, 256, 0, stream>>>((const float4*)accS, (float4*)d_out,
                                                          1.0f / (float)(L + 1), N);
}